// Round 6
// baseline (494.762 us; speedup 1.0000x reference)
//
#include <hip/hip_runtime.h>
#include <stdint.h>

#define SEQ    2048
#define HIDDEN 4096
#define NQH    32
#define NKVH   2
#define HD     128
#define QKVN   4608   // (32+4)*128
#define ATTN_N 4096   // 32*128

typedef short bf16x8 __attribute__((ext_vector_type(8)));
typedef float f32x4  __attribute__((ext_vector_type(4)));

#define ASYNC16(gp, lp) __builtin_amdgcn_global_load_lds( \
    (const __attribute__((address_space(1))) void*)(gp),  \
    (__attribute__((address_space(3))) void*)(lp), 16, 0, 0)

__device__ __forceinline__ float bf2f(unsigned short u) {
  union { unsigned int i; float f; } v; v.i = ((unsigned int)u) << 16; return v.f;
}
__device__ __forceinline__ unsigned short f2bf(float f) {
  union { float f; unsigned int i; } v; v.f = f;
  unsigned int r = v.i + 0x7fffu + ((v.i >> 16) & 1u);  // RNE
  return (unsigned short)(r >> 16);
}

// ================== fused prep: dtype-detect + all converts ===================
// ROUND-6: replaces detect_dtype (1-thread serial kernel) + to_bf16_any +
// 3x to_f32_any = 5 dispatches -> 1. Each block re-derives the dtype flag
// (thread 0: 64 L2-hot loads of hs[0..127] even idx; bf16 arrays have sane
// exponents, fp32-as-ushort has random exponent bits at even indices).
// Block 0 persists flag for downstream transpose64/gemm2 (in-stream order).
__global__ __launch_bounds__(256)
void prep_all(const void* __restrict__ hs_raw, const void* __restrict__ cos_raw,
              const void* __restrict__ sin_raw, const void* __restrict__ bias_raw,
              unsigned short* __restrict__ hs_c, float* __restrict__ cosf,
              float* __restrict__ sinf, float* __restrict__ biasf,
              int* __restrict__ flag_out) {
  __shared__ int sflag;
  if (threadIdx.x == 0) {
    const unsigned short* p = (const unsigned short*)hs_raw;
    int bad = 0;
    for (int i = 0; i < 128; i += 2) {
      const int e = (p[i] >> 7) & 0xFF;
      bad += (e < 100 || e > 140) ? 1 : 0;
    }
    sflag = (bad > 16) ? 1 : 0;
    if (blockIdx.x == 0) *flag_out = sflag;
  }
  __syncthreads();
  const int f = sflag;
  const int N0 = SEQ * HIDDEN / 4;            // hs -> bf16 (ushort4 units)
  const int N1 = N0 + SEQ * 64 / 4;           // cos -> f32
  const int N2 = N1 + SEQ * 64 / 4;           // sin -> f32
  const int N3 = N2 + QKVN / 4;               // bias -> f32
  for (int i = blockIdx.x * blockDim.x + threadIdx.x; i < N3; i += gridDim.x * blockDim.x) {
    if (i < N0) {
      if (f) {
        const float4 v = ((const float4*)hs_raw)[i];
        ushort4 u; u.x = f2bf(v.x); u.y = f2bf(v.y); u.z = f2bf(v.z); u.w = f2bf(v.w);
        ((ushort4*)hs_c)[i] = u;
      } else {
        ((ushort4*)hs_c)[i] = ((const ushort4*)hs_raw)[i];
      }
    } else {
      const void* src; float* dst; int j;
      if (i < N1)      { src = cos_raw;  dst = cosf;  j = i - N0; }
      else if (i < N2) { src = sin_raw;  dst = sinf;  j = i - N1; }
      else             { src = bias_raw; dst = biasf; j = i - N2; }
      if (f) {
        ((float4*)dst)[j] = ((const float4*)src)[j];
      } else {
        const ushort4 u = ((const ushort4*)src)[j];
        float4 v; v.x = bf2f(u.x); v.y = bf2f(u.y); v.z = bf2f(u.z); v.w = bf2f(u.w);
        ((float4*)dst)[j] = v;
      }
    }
  }
}

// ---- 64x64 transpose + convert: out[c][r] (bf16) = in[r][c]; in is R x C ----
// Read: 64B/thread (4x float4 or 2x 16B bf16). LDS rows padded to 72 ushorts
// (144B = 9x16B: keeps b128 writes aligned). Write-side: lanes differ only in
// output column -> column reads hit 32 distinct banks (conflict-free); 16B
// global stores; the 4 waves cover adjacent 16B row-segments so L2 assembles
// full lines.
__global__ __launch_bounds__(256)
void transpose64(const void* __restrict__ in, unsigned short* __restrict__ out,
                 int R, int C, const int* __restrict__ flag) {
  __shared__ __attribute__((aligned(16))) unsigned short t[64][72];
  const int r0 = blockIdx.y * 64, c0 = blockIdx.x * 64;
  const int lr = threadIdx.x >> 2;          // 0..63: input row
  const int lc = (threadIdx.x & 3) << 4;    // 0,16,32,48: input col segment
  bf16x8 v0, v1;
  if (*flag) {
    const float* src = (const float*)in + (size_t)(r0 + lr) * C + c0 + lc;
    const float4 f0 = ((const float4*)src)[0];
    const float4 f1 = ((const float4*)src)[1];
    const float4 f2 = ((const float4*)src)[2];
    const float4 f3 = ((const float4*)src)[3];
    v0[0] = f2bf(f0.x); v0[1] = f2bf(f0.y); v0[2] = f2bf(f0.z); v0[3] = f2bf(f0.w);
    v0[4] = f2bf(f1.x); v0[5] = f2bf(f1.y); v0[6] = f2bf(f1.z); v0[7] = f2bf(f1.w);
    v1[0] = f2bf(f2.x); v1[1] = f2bf(f2.y); v1[2] = f2bf(f2.z); v1[3] = f2bf(f2.w);
    v1[4] = f2bf(f3.x); v1[5] = f2bf(f3.y); v1[6] = f2bf(f3.z); v1[7] = f2bf(f3.w);
  } else {
    const unsigned short* src = (const unsigned short*)in + (size_t)(r0 + lr) * C + c0 + lc;
    v0 = *(const bf16x8*)src;
    v1 = *(const bf16x8*)(src + 8);
  }
  *(bf16x8*)&t[lr][lc]     = v0;
  *(bf16x8*)&t[lr][lc + 8] = v1;
  __syncthreads();
  const int oc = threadIdx.x & 63;          // output row (= input col)
  const int rb = (threadIdx.x >> 6) * 8;    // r-segment base per wave
#pragma unroll
  for (int it = 0; it < 2; ++it) {
    const int rseg = rb + it * 32;
    bf16x8 w;
#pragma unroll
    for (int j = 0; j < 8; j++) w[j] = (short)t[rseg + j][oc];
    *(bf16x8*)(out + (size_t)(c0 + oc) * R + r0 + rseg) = w;
  }
}

// ------------- C = A(MxK) * Bt(NxK)^T (+bias), bf16 in, fp32 acc --------------
// m97 structure, 128x128 tile, BK=64 as two 32-k sub-tiles per barrier-pair.
// At this problem's shapes the m97 family is at its per-CU ceiling (~3.6 TF/CU,
// matching learn_hip full-fill m97); deficit vs 912 TF is grid quantization.
// Rounds 1-3 (8-phase 256^2, 2-phase 256x128, triple-buffer) all regressed.
// CLOSED — do not touch.
__global__ __launch_bounds__(256, 2)
void gemm_bt(const unsigned short* __restrict__ A,
             const unsigned short* __restrict__ Bt,
             const float* __restrict__ bias,
             void* __restrict__ C,
             int M, int N, int K, const int* __restrict__ of32) {
  __shared__ __attribute__((aligned(16))) unsigned short As[2][128 * 32];
  __shared__ __attribute__((aligned(16))) unsigned short Bs[2][128 * 32];
  const int tid  = threadIdx.x;
  const int wave = tid >> 6, lane = tid & 63;
  const int quad = lane >> 4, l16 = lane & 15;
  const int m0 = blockIdx.y * 128, n0 = blockIdx.x * 128;
  const int wm = (wave >> 1) * 64, wn = (wave & 1) * 64;

  // thread t stages row=t/4, swizzled k-chunk g=(t&3)^((row>>1)&3); LDS = t*16B
  const int crow = tid >> 2;
  const int gsw = ((tid & 3) ^ ((crow >> 1) & 3)) << 3;
  const unsigned short* gA = A + (size_t)(m0 + crow) * K + gsw;
  const unsigned short* gB = Bt + (size_t)(n0 + crow) * K + gsw;
  const size_t r64 = (size_t)64 * K;
  const int l8 = tid * 8;

  // frag-read swizzled chunk offset (elements)
  const int cxor = (quad ^ ((l16 >> 1) & 3)) << 3;

  f32x4 acc[4][4] = {};

  for (int k0 = 0; k0 < K; k0 += 64) {
    __syncthreads();                 // prev iter's LDS reads done
    ASYNC16(gA + k0,            &As[0][l8]);
    ASYNC16(gA + r64 + k0,      &As[0][l8 + 2048]);
    ASYNC16(gA + k0 + 32,       &As[1][l8]);
    ASYNC16(gA + r64 + k0 + 32, &As[1][l8 + 2048]);
    ASYNC16(gB + k0,            &Bs[0][l8]);
    ASYNC16(gB + r64 + k0,      &Bs[0][l8 + 2048]);
    ASYNC16(gB + k0 + 32,       &Bs[1][l8]);
    ASYNC16(gB + r64 + k0 + 32, &Bs[1][l8 + 2048]);
    __syncthreads();                 // drains vmcnt: both halves visible
#pragma unroll
    for (int h = 0; h < 2; h++) {
      bf16x8 aF[4], bF[4];
#pragma unroll
      for (int i = 0; i < 4; i++)
        aF[i] = *(const bf16x8*)&As[h][(wm + i * 16 + l16) * 32 + cxor];
#pragma unroll
      for (int j = 0; j < 4; j++)
        bF[j] = *(const bf16x8*)&Bs[h][(wn + j * 16 + l16) * 32 + cxor];
#pragma unroll
      for (int i = 0; i < 4; i++)
#pragma unroll
        for (int j = 0; j < 4; j++)
          acc[i][j] = __builtin_amdgcn_mfma_f32_16x16x32_bf16(aF[i], bF[j], acc[i][j], 0, 0, 0);
    }
  }

  const int wf32 = of32 ? *of32 : 0;
#pragma unroll
  for (int j = 0; j < 4; j++) {
    const int col = n0 + wn + j * 16 + l16;
    const float bv = bias ? bias[col] : 0.0f;
#pragma unroll
    for (int i = 0; i < 4; i++) {
#pragma unroll
      for (int r = 0; r < 4; r++) {
        const int row = m0 + wm + i * 16 + quad * 4 + r;   // C/D: row=quad*4+reg, col=l16
        const float v = acc[i][j][r] + bv;
        const size_t off = (size_t)row * N + col;
        if (wf32) ((float*)C)[off] = v;
        else      ((unsigned short*)C)[off] = f2bf(v);
      }
    }
  }
}

// --------- RoPE (interleaved) + split into Q (scaled), K, V^T buffers ---------
// Vectorized: bf16x8 loads (16B/thread), float4 cos/sin, bf16x8 Q/K stores.
// V (no rope) stays scalar-scattered (1/18 of elements, transposed).
__global__ void rope_split(const unsigned short* __restrict__ qkv,
                           const float* __restrict__ cosb,
                           const float* __restrict__ sinb,
                           unsigned short* __restrict__ qb,
                           unsigned short* __restrict__ kb,
                           unsigned short* __restrict__ vtb) {
  const int s = blockIdx.x;
  const unsigned short* row = qkv + (size_t)s * QKVN;
  const float sc = 0.08838834764831845f * 1.44269504088896341f;  // 1/sqrt(128)*log2(e)
  for (int p8 = threadIdx.x; p8 < QKVN / 8; p8 += blockDim.x) {
    const int col = p8 << 3;          // 8 consecutive elems, within one head
    const int head = col >> 7;
    const int d = col & 127;
    const bf16x8 x = *(const bf16x8*)&row[col];
    if (head >= NQH + NKVH) {         // V: transposed copy, no rope
      const int vh = head - NQH - NKVH;
      unsigned short* vp = vtb + (size_t)vh * HD * SEQ + (size_t)d * SEQ + s;
#pragma unroll
      for (int j = 0; j < 8; j++) vp[(size_t)j * SEQ] = (unsigned short)x[j];
      continue;
    }
    float y[8];
#pragma unroll
    for (int j = 0; j < 8; j++) y[j] = bf2f((unsigned short)x[j]);
    if (d < 64) {
      const float4 c4 = *(const float4*)&cosb[s * 64 + (d >> 1)];
      const float4 s4 = *(const float4*)&sinb[s * 64 + (d >> 1)];
      const float cc[4] = {c4.x, c4.y, c4.z, c4.w};
      const float ss[4] = {s4.x, s4.y, s4.z, s4.w};
#pragma unroll
      for (int q = 0; q < 4; q++) {
        const float x0 = y[2 * q], x1 = y[2 * q + 1];
        y[2 * q]     = x0 * cc[q] - x1 * ss[q];
        y[2 * q + 1] = x1 * cc[q] + x0 * ss[q];
      }
    }
    bf16x8 o;
    if (head < NQH) {
#pragma unroll
      for (int j = 0; j < 8; j++) o[j] = (short)f2bf(y[j] * sc);
      *(bf16x8*)&qb[(size_t)head * SEQ * HD + (size_t)s * HD + d] = o;
    } else {
#pragma unroll
      for (int j = 0; j < 8; j++) o[j] = (short)f2bf(y[j]);
      *(bf16x8*)&kb[(size_t)(head - NQH) * SEQ * HD + (size_t)s * HD + d] = o;
    }
  }
}

// ------------------- causal flash attention, bf16 MFMA ------------------------
// grid (32 heads, 32 q-tiles of 64 rows), heavy-first. 4 waves/block, 16 rows/wave.
// Double-buffered K/V, single barrier per K-tile. plds wave-private (no
// barriers). Row-sums of P via ones-B-frag MFMA.
__global__ __launch_bounds__(256, 2)
void attn_fwd(const unsigned short* __restrict__ qb,
              const unsigned short* __restrict__ kb,
              const unsigned short* __restrict__ vtb,
              unsigned short* __restrict__ ob) {
  const int h = blockIdx.x;
  const int qt = 31 - (int)blockIdx.y;            // heavy-first scheduling
  const int tid = threadIdx.x;
  const int wave = tid >> 6, lane = tid & 63;
  const int quad = lane >> 4, l16 = lane & 15;
  const int q0 = qt * 64 + wave * 16;
  const unsigned short* qh  = qb  + (size_t)h * SEQ * HD;
  const unsigned short* kh  = kb  + (size_t)(h >> 4) * SEQ * HD;
  const unsigned short* vth = vtb + (size_t)(h >> 4) * HD * SEQ;

  __shared__ __attribute__((aligned(16))) unsigned short Ks[2][64 * 128];  // [key][d], chunk-swizzled
  __shared__ __attribute__((aligned(16))) unsigned short Vs[2][128 * 64];  // [d][key], chunk-swizzled
  __shared__ __attribute__((aligned(16))) unsigned short plds[4][16][80];  // wave-private

  bf16x8 qf[4];
#pragma unroll
  for (int kbk = 0; kbk < 4; kbk++)   // A-frag: A[m=l16][k=quad*8+j]
    qf[kbk] = *(const bf16x8*)&qh[(size_t)(q0 + l16) * HD + kbk * 32 + quad * 8];

  bf16x8 onesf;
#pragma unroll
  for (int i = 0; i < 8; i++) onesf[i] = (short)0x3F80;   // bf16 1.0

  f32x4 oacc[8] = {};
  f32x4 lacc = {};
  float mrow[4] = {-1e30f, -1e30f, -1e30f, -1e30f};

  // stage tile kt_ into buffer bsel: 8 global_load_lds per thread
#define STAGEKV(kt_, bsel) do {                                                  \
    const int kb_ = (kt_) * 64;                                                  \
    _Pragma("unroll")                                                            \
    for (int c = 0; c < 4; c++) {                                                \
      const int j = c * 256 + tid;                                               \
      const int key = j >> 4;                                                    \
      const int g = (j & 15) ^ (key & 15);                                       \
      ASYNC16(kh + (size_t)(kb_ + key) * HD + g * 8, &Ks[bsel][0] + j * 8);      \
    }                                                                            \
    _Pragma("unroll")                                                            \
    for (int c = 0; c < 4; c++) {                                                \
      const int j = c * 256 + tid;                                               \
      const int d = j >> 3;                                                      \
      const int g = (j & 7) ^ (d & 7);                                           \
      ASYNC16(vth + (size_t)d * SEQ + kb_ + g * 8, &Vs[bsel][0] + j * 8);        \
    }                                                                            \
  } while (0)

  STAGEKV(0, 0);

  for (int kt = 0; kt <= qt; kt++) {
    const int b = kt & 1;
    const int kbase = kt * 64;
    __syncthreads();                   // drains vmcnt: tile kt visible to all;
                                       // all waves done with iter kt-1 reads
    if (kt < qt) STAGEKV(kt + 1, b ^ 1);   // in flight under this tile's compute

    f32x4 sv[4] = {};
#pragma unroll
    for (int kbk = 0; kbk < 4; kbk++) {
#pragma unroll
      for (int t = 0; t < 4; t++) {
        bf16x8 kf = *(const bf16x8*)&Ks[b][(t * 16 + l16) * 128 + (((kbk << 2) + quad) ^ l16) * 8];
        sv[t] = __builtin_amdgcn_mfma_f32_16x16x32_bf16(qf[kbk], kf, sv[t], 0, 0, 0);
      }
    }
    if (kt == qt) {   // diagonal tile masking
#pragma unroll
      for (int t = 0; t < 4; t++) {
        const int key = kbase + t * 16 + l16;
#pragma unroll
        for (int r = 0; r < 4; r++)
          if (key > q0 + quad * 4 + r) sv[t][r] = -1e30f;
      }
    }
    float alpha[4];
#pragma unroll
    for (int r = 0; r < 4; r++) {
      float mx = fmaxf(fmaxf(sv[0][r], sv[1][r]), fmaxf(sv[2][r], sv[3][r]));
#pragma unroll
      for (int off = 8; off; off >>= 1) mx = fmaxf(mx, __shfl_xor(mx, off));
      const float mnew = fmaxf(mrow[r], mx);
      alpha[r] = __builtin_exp2f(mrow[r] - mnew);
      mrow[r] = mnew;
#pragma unroll
      for (int t = 0; t < 4; t++)
        sv[t][r] = __builtin_exp2f(sv[t][r] - mnew);
    }
#pragma unroll
    for (int dt = 0; dt < 8; dt++)
#pragma unroll
      for (int r = 0; r < 4; r++) oacc[dt][r] *= alpha[r];
#pragma unroll
    for (int r = 0; r < 4; r++) lacc[r] *= alpha[r];
    // P: C-layout -> A-layout via wave-private LDS round-trip (no barriers)
#pragma unroll
    for (int r = 0; r < 4; r++)
#pragma unroll
      for (int t = 0; t < 4; t++)
        plds[wave][quad * 4 + r][t * 16 + l16] = f2bf(sv[t][r]);
    bf16x8 pf0 = *(const bf16x8*)&plds[wave][l16][quad * 8];
    bf16x8 pf1 = *(const bf16x8*)&plds[wave][l16][32 + quad * 8];
    // row-sum of P via ones B-frag: lacc[r] += sum_k P[row][k] (replicated over l16)
    lacc = __builtin_amdgcn_mfma_f32_16x16x32_bf16(pf0, onesf, lacc, 0, 0, 0);
    lacc = __builtin_amdgcn_mfma_f32_16x16x32_bf16(pf1, onesf, lacc, 0, 0, 0);
#pragma unroll
    for (int dt = 0; dt < 8; dt++) {
      const int vrow = (dt * 16 + l16) * 64;
      bf16x8 vf0 = *(const bf16x8*)&Vs[b][vrow + ((quad) ^ (l16 & 7)) * 8];
      oacc[dt] = __builtin_amdgcn_mfma_f32_16x16x32_bf16(pf0, vf0, oacc[dt], 0, 0, 0);
      bf16x8 vf1 = *(const bf16x8*)&Vs[b][vrow + ((4 + quad) ^ (l16 & 7)) * 8];
      oacc[dt] = __builtin_amdgcn_mfma_f32_16x16x32_bf16(pf1, vf1, oacc[dt], 0, 0, 0);
    }
  }
#undef STAGEKV
#pragma unroll
  for (int dt = 0; dt < 8; dt++) {
#pragma unroll
    for (int r = 0; r < 4; r++) {
      const float v = oacc[dt][r] / lacc[r];
      ob[(size_t)(q0 + quad * 4 + r) * ATTN_N + h * HD + dt * 16 + l16] = f2bf(v);
    }
  }
}

extern "C" void kernel_launch(void* const* d_in, const int* in_sizes, int n_in,
                              void* d_out, int out_size, void* d_ws, size_t ws_size,
                              hipStream_t stream) {
  const void* hs_raw   = d_in[0];
  const void* cos_raw  = d_in[1];
  const void* sin_raw  = d_in[2];
  const void* wqkv_raw = d_in[3];
  const void* bqkv_raw = d_in[4];
  const void* wo_raw   = d_in[5];
  unsigned short* ws = (unsigned short*)d_ws;

  unsigned short* R1   = ws;                           // wt_qkv -> q/k/vt bufs -> wt_o
  unsigned short* R2   = R1 + (size_t)QKVN * HIDDEN;   // qkv -> attnb
  unsigned short* hs_c = R2 + (size_t)SEQ * QKVN;
  float* cosf  = (float*)(hs_c + (size_t)SEQ * HIDDEN);
  float* sinf  = cosf + SEQ * 64;
  float* biasf = sinf + SEQ * 64;
  int*   flag  = (int*)(biasf + QKVN);

  unsigned short* wt_qkv = R1;
  unsigned short* qbuf   = R1;
  unsigned short* kbuf   = qbuf + (size_t)NQH * SEQ * HD;
  unsigned short* vtbuf  = kbuf + (size_t)NKVH * SEQ * HD;
  unsigned short* wt_o   = R1;
  unsigned short* qkv    = R2;
  unsigned short* attnb  = R2;

  // 7 dispatches (was 11): fused prep removes detect + 4 converts
  prep_all<<<2048, 256, 0, stream>>>(hs_raw, cos_raw, sin_raw, bqkv_raw,
                                     hs_c, cosf, sinf, biasf, flag);
  transpose64<<<dim3(QKVN / 64, HIDDEN / 64), 256, 0, stream>>>(wqkv_raw, wt_qkv, HIDDEN, QKVN, flag);
  gemm_bt<<<dim3(QKVN / 128, SEQ / 128), 256, 0, stream>>>(hs_c, wt_qkv, biasf, qkv, SEQ, QKVN, HIDDEN, nullptr);
  rope_split<<<SEQ, 256, 0, stream>>>(qkv, cosf, sinf, qbuf, kbuf, vtbuf);
  attn_fwd<<<dim3(NQH, SEQ / 64), 256, 0, stream>>>(qbuf, kbuf, vtbuf, attnb);
  transpose64<<<dim3(ATTN_N / 64, HIDDEN / 64), 256, 0, stream>>>(wo_raw, wt_o, HIDDEN, ATTN_N, flag);
  gemm_bt<<<dim3(ATTN_N / 128, SEQ / 128), 256, 0, stream>>>(attnb, wt_o, nullptr, d_out, SEQ, ATTN_N, HIDDEN, flag);
}